// Round 6
// baseline (90.968 us; speedup 1.0000x reference)
//
#include <hip/hip_runtime.h>
#include <math.h>

// ============================================================================
// PROBE ROUND 3 (decisive): real R5 kernel (correct output) + an EMPTY kernel
// at the identical grid/block config. dur_us - 90.3 = T(empty) = per-launch
// fixed cost (graph-node + 1800-WG dispatch ramp/drain). Three structurally
// diverse kernels all measured 16.4-17.6 us slope; resource floor is ~9 us;
// this probe splits the slope into {launch overhead | genuine device time}.
// ============================================================================

constexpr int kC = 92, kT = 960;
constexpr int kBN = 14400;            // 16*900 rows
constexpr int WPB = 8;                // waves per block (independent rows)
constexpr int THREADS = WPB * 64;     // 512

__global__ __launch_bounds__(THREADS) void empty_kernel() {
    // Immediate return: measures pure dispatch/launch cost at grid=1800x512.
}

__global__ __launch_bounds__(THREADS, 6) void matcher_kernel(
    const float* __restrict__ out_labels,   // [BN, C]
    const float* __restrict__ out_bboxes,   // [BN, 4] cxcywh
    const int*   __restrict__ tgt_labels,   // [T]
    const float* __restrict__ tgt_bboxes,   // [T, 4] used as-is (xyxy per ref NOTE)
    float*       __restrict__ cost)         // [BN, T]
{
    // per-wave class-cost row: s_cls[w][c] = 5 - prob(c). stride 96 pads banks.
    __shared__ float s_cls[WPB][96];        // 3 KB

    const int tid  = threadIdx.x;
    const int w    = tid >> 6;
    const int lane = tid & 63;
    const int p    = blockIdx.x * WPB + w;  // this wave's row (always < kBN)

    // ---- softmax over C=92 (lanes cover [0,64) + [64,92)), no max-sub ----
    const float* lrow = out_labels + (size_t)p * kC;
    float e0 = __expf(lrow[lane]);                               // lane < 92 always
    float e1 = (lane + 64 < kC) ? __expf(lrow[lane + 64]) : 0.0f;
    float s = e0 + e1;
    #pragma unroll
    for (int m = 1; m < 64; m <<= 1)
        s += __shfl_xor(s, m, 64);          // butterfly: every lane has full sum
    float inv = __builtin_amdgcn_rcpf(s);   // ~1e-5 rel err, fine at 0.5 tol
    s_cls[w][lane] = fmaf(-e0, inv, 5.0f);  // 5 - prob
    if (lane + 64 < kC) s_cls[w][lane + 64] = fmaf(-e1, inv, 5.0f);

    // ---- row bbox: uniform-address load, register-resident in all lanes ----
    float4 bb = ((const float4*)out_bboxes)[p];     // cx,cy,w,h
    float hw = 0.5f * bb.z, hh = 0.5f * bb.w;
    float bx0 = bb.x - hw, by0 = bb.y - hh;
    float bx1 = bb.x + hw, by1 = bb.y + hh;
    float area1 = (bx1 - bx0) * (by1 - by0);

    // make this wave's LDS writes visible to its own ds_reads below
    asm volatile("s_waitcnt lgkmcnt(0)" ::: "memory");

    // ---- pair phase: 15 targets/lane, t = lane + 64k (fully coalesced) ----
    const float4* tb4 = (const float4*)tgt_bboxes;
    float* crow = cost + (size_t)p * kT;
    #pragma unroll 5
    for (int k = 0; k < 15; ++k) {
        const int t = lane + 64 * k;
        float4 tbb = tb4[t];                 // L1-resident after first block
        int    lb  = tgt_labels[t];
        float  cls = s_cls[w][lb];           // random-bank gather, ~2-way avg
        float  a2  = (tbb.z - tbb.x) * (tbb.w - tbb.y);
        // L1 on raw cxcywh vs target (torch.cdist p=1 semantics)
        float l1 = fabsf(bb.x - tbb.x) + fabsf(bb.y - tbb.y)
                 + fabsf(bb.z - tbb.z) + fabsf(bb.w - tbb.w);
        // intersection (clamp needed)
        float ltx = fmaxf(bx0, tbb.x), lty = fmaxf(by0, tbb.y);
        float rbx = fminf(bx1, tbb.z), rby = fminf(by1, tbb.w);
        float iw = fmaxf(rbx - ltx, 0.0f), ih = fmaxf(rby - lty, 0.0f);
        float inter = iw * ih;
        float uni = area1 + a2 - inter;
        // enclosing box (clamp is a no-op: pred w,h >= 0)
        float ex0 = fminf(bx0, tbb.x), ey0 = fminf(by0, tbb.y);
        float ex1 = fmaxf(bx1, tbb.z), ey1 = fmaxf(by1, tbb.w);
        float area_e = (ex1 - ex0) * (ey1 - ey0);
        // cost = (5-prob) + 5*L1 - 2*(inter*area_e + uni^2)/(uni*area_e)
        float num = fmaf(uni, uni, inter * area_e);
        float rcp = __builtin_amdgcn_rcpf(uni * area_e);
        float v = fmaf(5.0f, l1, cls);
        v = fmaf(-2.0f * num, rcp, v);
        crow[t] = v;                         // lanes contiguous -> 256B/inst
    }
}

extern "C" void kernel_launch(void* const* d_in, const int* in_sizes, int n_in,
                              void* d_out, int out_size, void* d_ws, size_t ws_size,
                              hipStream_t stream) {
    const float* out_labels = (const float*)d_in[0];
    const float* out_bboxes = (const float*)d_in[1];
    const int*   tgt_labels = (const int*)d_in[2];
    const float* tgt_bboxes = (const float*)d_in[3];
    float* cost = (float*)d_out;
    dim3 grid(kBN / WPB);   // 14400/8 = 1800 blocks
    // Real kernel: identical to R5 (correct output, 90.3 us config).
    matcher_kernel<<<grid, THREADS, 0, stream>>>(out_labels, out_bboxes,
                                                 tgt_labels, tgt_bboxes, cost);
    // PROBE: empty kernel, same grid. dur_us - 90.3 = per-launch fixed cost.
    empty_kernel<<<grid, THREADS, 0, stream>>>();
}